// Round 10
// baseline (201.746 us; speedup 1.0000x reference)
//
#include <hip/hip_runtime.h>
#include <math.h>

// Problem constants: B=4, L=T=2048, H=8, E=64, C=H*E=512, top_k=7
// Output = cumsum(V) with top-7 rows (by corrmean) replaced by running mean.
// R6: symmetric gram -> upper-triangle tiles. R9: cumsum psum/write split.
// R10/R11: 256x256 deep pipelines REGRESSED (out of regime at K=512).
// R12: (256,4) clamp -> spills. R13: fusions, 188.0. R14: 3-slot ring +
//     counted vmcnt(4): temporal 56.2, total 182.8. BEST.
// R16: depth-3 -> 67.5 (occupancy binding; depth axis closed).
// R17: 3-launch + atomicAdd epilogue + redundant top-7: temporal 60.6,
//     total 187.2. CALIBRATION: total = temporal_dispatch + 126.6 exactly
//     (R14/R16/R17). Launch count is a dead lever; atomics cost +4.4.
// R18 (this round): (a) revert epilogue to R14 plain stores + merge_row;
//     (b) OVERLAP the bulk cumsum write with the gram: tail blocks
//     2368..2879 of the temporal launch write plain cumsum (psum ready
//     from L1; no top-7 dependency), tiny fixup kernel (32 blocks)
//     rewrites the 7 special rows after combine. 5 launches:
//     L1 convert+psum | L2 gram+instance+bulkwrite | L3 merge | L4 combine
//     | L5 fixup.

typedef __attribute__((ext_vector_type(8))) short short8;
typedef __attribute__((ext_vector_type(8))) unsigned short ushort8;
typedef __attribute__((ext_vector_type(4))) float f32x4;

typedef const __attribute__((address_space(1))) void* gas_ptr;
typedef __attribute__((address_space(3))) void* las_ptr;

#define EXP_OFF 80.0f

__device__ __forceinline__ void async_cp16(const void* g, void* l) {
  // LDS dest is wave-uniform base; HW adds lane*16 (m104/m108).
  __builtin_amdgcn_global_load_lds((gas_ptr)g, (las_ptr)l, 16, 0, 0);
}

__device__ __forceinline__ unsigned short f2bf(float x) {
  union { float f; unsigned int u; } v; v.f = x;
  unsigned int r = v.u + 0x7FFFu + ((v.u >> 16) & 1u);  // RNE
  return (unsigned short)(r >> 16);
}

// ---------------------------------------------------------------------------
// L1. Blocks 0..4095: convert Q,K fp32 -> Z bf16 [4][4096][512].
// Blocks 4096..4607: cumsum psum phase (reads V only; psum[bh][g][64]).
// ---------------------------------------------------------------------------
__global__ __launch_bounds__(256) void convert_psum_kernel(
    const float* __restrict__ Q, const float* __restrict__ K,
    unsigned short* __restrict__ Z, const float* __restrict__ V,
    float* __restrict__ psum) {
  if (blockIdx.x >= 4096) {
    int gb = (blockIdx.x - 4096) * 4 + (threadIdx.x >> 6);  // 0..2047
    int bh = gb >> 6, g = gb & 63;
    int h = bh & 7, b = bh >> 3;
    int lane = threadIdx.x & 63;
    int ro = lane >> 4, e4 = (lane & 15) * 4;
    const float* base =
        V + (size_t)(b * 2048 + g * 32 + ro) * 512 + h * 64 + e4;
    float sx = 0.f, sy = 0.f, sz = 0.f, sw = 0.f;
#pragma unroll
    for (int k = 0; k < 8; k++) {
      float4 v = *(const float4*)(base + (size_t)(k * 4) * 512);
      sx += v.x; sy += v.y; sz += v.z; sw += v.w;
    }
    sx += __shfl_xor(sx, 16); sy += __shfl_xor(sy, 16);
    sz += __shfl_xor(sz, 16); sw += __shfl_xor(sw, 16);
    sx += __shfl_xor(sx, 32); sy += __shfl_xor(sy, 32);
    sz += __shfl_xor(sz, 32); sw += __shfl_xor(sw, 32);
    if (ro == 0) {
      float4 o = {sx, sy, sz, sw};
      *(float4*)(psum + ((size_t)bh * 64 + g) * 64 + e4) = o;
    }
    return;
  }

  int tid = blockIdx.x * 256 + threadIdx.x;  // 0..1048575
  int row = tid >> 6;                        // b*4096 + i
  int c0 = (tid & 63) * 8;
  int b = row >> 12, i = row & 4095;
  const float* src = (i < 2048)
      ? Q + ((size_t)(b * 2048 + i) * 512 + c0)
      : K + ((size_t)(b * 2048 + (i - 2048)) * 512 + c0);
  float4 v0 = ((const float4*)src)[0];
  float4 v1 = ((const float4*)src)[1];
  ushort8 o;
  o[0] = f2bf(v0.x); o[1] = f2bf(v0.y); o[2] = f2bf(v0.z); o[3] = f2bf(v0.w);
  o[4] = f2bf(v1.x); o[5] = f2bf(v1.y); o[6] = f2bf(v1.z); o[7] = f2bf(v1.w);
  *(ushort8*)(Z + (size_t)row * 512 + c0) = o;
}

// ---------------------------------------------------------------------------
// L2. Blocks 0..2111: temporal gram, R14-verbatim (128x128 tiles, 16x16x32
// bf16 MFMA, BK=32, 3-slot LDS ring, counted vmcnt(4), one s_barrier/kc,
// plain part stores). Blocks 2112..2367: instance-LSE. Blocks 2368..2879:
// BULK cumsum write (plain cumsum of V into out; psum ready from L1;
// top-7 rows fixed up later by fixup_kernel). __launch_bounds__(256,3).
// ---------------------------------------------------------------------------
__global__ __launch_bounds__(256, 3) void temporal_gemm_kernel(
    const unsigned short* __restrict__ Z, float* __restrict__ part,
    float* __restrict__ lse_inst /* [2048][8] */,
    float* __restrict__ posdot /* [4][2048] */,
    const float* __restrict__ V, const float* __restrict__ psum,
    float* __restrict__ out) {
  __shared__ __align__(16) unsigned short As[3][128 * 32];  // 3 x 8 KB
  __shared__ __align__(16) unsigned short Bs[3][128 * 32];  // 3 x 8 KB

  if (blockIdx.x >= 2368) {
    // ---------------- bulk cumsum write (no specials) ---------------------
    int w2 = blockIdx.x - 2368;       // 0..511
    int bh = w2 >> 4, chunk = w2 & 15;
    int h = bh & 7, b = bh >> 3;
    int tid = threadIdx.x;
    int e = tid & 63, sub = tid >> 6;
    int g = chunk * 4 + sub;          // 0..63

    const float* ps = psum + (size_t)bh * 64 * 64;
    float run = 0.f;
    for (int gg = 0; gg < g; ++gg) run += ps[gg * 64 + e];

    const float* Vbase = V + (size_t)(b * 2048) * 512 + h * 64 + e;
    float* obase = out + (size_t)bh * 2048 * 64 + e;

    int l0 = g * 32;
#pragma unroll 4
    for (int l = l0; l < l0 + 32; ++l) {
      run += Vbase[(size_t)l * 512];
      obase[(size_t)l * 64] = run;
    }
    return;
  }

  if (blockIdx.x >= 2112) {
    // ---------------- instance path ---------------------------------------
    int wave = ((blockIdx.x - 2112) * 256 + threadIdx.x) >> 6;  // 0..1023
    int t0 = wave * 2;
    int lane = threadIdx.x & 63;
    int lm = lane & 15, q = lane >> 4;
    int tt = (lm < 8) ? t0 : t0 + 1;
    int v = lm & 7;
    size_t zrow = (v < 4) ? ((size_t)v * 4096 + tt)
                          : ((size_t)(v - 4) * 4096 + 2048 + tt);
    const unsigned short* g = Z + zrow * 512 + q * 8;

    f32x4 acc0 = (f32x4)(0.f), acc1 = (f32x4)(0.f);
#pragma unroll
    for (int kc = 0; kc < 16; kc += 2) {
      short8 a0 = *(const short8*)(g + kc * 32);
      short8 a1 = *(const short8*)(g + kc * 32 + 32);
      acc0 = __builtin_amdgcn_mfma_f32_16x16x32_bf16(a0, a0, acc0, 0, 0, 0);
      acc1 = __builtin_amdgcn_mfma_f32_16x16x32_bf16(a1, a1, acc1, 0, 0, 0);
    }
    f32x4 acc = acc0 + acc1;

#pragma unroll
    for (int rr = 0; rr < 4; rr++) {
      int i = q * 4 + rr;                      // row 0..15
      float val = acc[rr];
      bool samehalf = ((i < 8) == (lm < 8));
      int t = (i < 8) ? t0 : t0 + 1;
      int iv = i & 7;
      if (samehalf && iv < 4 && (lm & 7) == iv + 4)
        posdot[iv * 2048 + t] = val;
      float dd = (samehalf && lm != i) ? val : -INFINITY;
      float mt = dd;
      mt = fmaxf(mt, __shfl_xor(mt, 1));
      mt = fmaxf(mt, __shfl_xor(mt, 2));
      mt = fmaxf(mt, __shfl_xor(mt, 4));
      float e = __expf(dd - mt);
      e += __shfl_xor(e, 1);
      e += __shfl_xor(e, 2);
      e += __shfl_xor(e, 4);
      if ((lm & 7) == 0 && samehalf) lse_inst[t * 8 + iv] = mt + __logf(e);
    }
    return;
  }

  // ------------------------- gram path (R14 verbatim) ---------------------
  int id = blockIdx.x;                  // 0..2111
  int x = id & 7;
  int b = x >> 1;                       // XCD-pair lock per batch
  int t = (id >> 3) * 2 + (x & 1);      // 0..527
  // invert t = cj*(cj+1)/2 + ri, ri<=cj
  int cj = (int)((sqrtf(8.0f * (float)t + 1.0f) - 1.0f) * 0.5f);
  while ((cj + 1) * (cj + 2) / 2 <= t) cj++;
  while (cj * (cj + 1) / 2 > t) cj--;
  int ri = t - cj * (cj + 1) / 2;
  const unsigned short* Zb = Z + (size_t)b * 4096 * 512;

  int tid = threadIdx.x;
  int w = tid >> 6, lane = tid & 63;
  int wr = w >> 1, wc = w & 1;
  int lm = lane & 15, q = lane >> 4;
  int swz = q ^ ((lm >> 1) & 3);  // frag-read physical chunk

  int srow = lane >> 2;
  int kq = (lane & 3) ^ ((lane >> 3) & 3);
  int rl0 = w * 16 + srow;
  int rl1 = 64 + rl0;
  const unsigned short* gA0 = Zb + (size_t)(ri * 128 + rl0) * 512 + kq * 8;
  const unsigned short* gA1 = Zb + (size_t)(ri * 128 + rl1) * 512 + kq * 8;
  const unsigned short* gB0 = Zb + (size_t)(cj * 128 + rl0) * 512 + kq * 8;
  const unsigned short* gB1 = Zb + (size_t)(cj * 128 + rl1) * 512 + kq * 8;
  int lo0 = (w * 16) * 32;        // wave-uniform base offsets
  int lo1 = (64 + w * 16) * 32;

  f32x4 acc[4][4];
#pragma unroll
  for (int mi = 0; mi < 4; mi++)
#pragma unroll
    for (int ni = 0; ni < 4; ni++) acc[mi][ni] = (f32x4)(0.f);

#define STAGE(kc_, sl_)                                  \
  do {                                                   \
    int go_ = (kc_) * 32;                                \
    async_cp16(gA0 + go_, As[sl_] + lo0);                \
    async_cp16(gA1 + go_, As[sl_] + lo1);                \
    async_cp16(gB0 + go_, Bs[sl_] + lo0);                \
    async_cp16(gB1 + go_, Bs[sl_] + lo1);                \
  } while (0)

  // Prologue: tiles 0,1 into slots 0,1 (8 loads outstanding per wave).
  STAGE(0, 0);
  STAGE(1, 1);

  int sl = 0;  // ring slot holding tile kc
  for (int kc = 0; kc < 16; ++kc) {
    if (kc < 15)
      asm volatile("s_waitcnt vmcnt(4)" ::: "memory");
    else
      asm volatile("s_waitcnt vmcnt(0)" ::: "memory");
    asm volatile("s_barrier" ::: "memory");

    if (kc + 2 < 16) {
      int ss = sl + 2;
      if (ss >= 3) ss -= 3;
      STAGE(kc + 2, ss);
    }

    short8 af[4], bfr[4];
#pragma unroll
    for (int mi = 0; mi < 4; mi++) {
      int ar = wr * 64 + mi * 16 + lm;
      af[mi] = *(const short8*)(As[sl] + ar * 32 + swz * 8);
    }
#pragma unroll
    for (int ni = 0; ni < 4; ni++) {
      int bc = wc * 64 + ni * 16 + lm;
      bfr[ni] = *(const short8*)(Bs[sl] + bc * 32 + swz * 8);
    }
#pragma unroll
    for (int mi = 0; mi < 4; mi++)
#pragma unroll
      for (int ni = 0; ni < 4; ni++)
        acc[mi][ni] = __builtin_amdgcn_mfma_f32_16x16x32_bf16(
            af[mi], bfr[ni], acc[mi][ni], 0, 0, 0);

    sl = (sl + 1 == 3) ? 0 : sl + 1;
  }
#undef STAGE

  // Epilogue. C/D layout: col=lane&15, row=(lane>>4)*4+reg (m89-verified).
  float rsum[4][4];
  float csum[4];
#pragma unroll
  for (int mi = 0; mi < 4; mi++)
#pragma unroll
    for (int rr = 0; rr < 4; rr++) rsum[mi][rr] = 0.f;
#pragma unroll
  for (int ni = 0; ni < 4; ni++) csum[ni] = 0.f;

#pragma unroll
  for (int mi = 0; mi < 4; mi++) {
#pragma unroll
    for (int ni = 0; ni < 4; ni++) {
#pragma unroll
      for (int rr = 0; rr < 4; rr++) {
        int R = ri * 128 + wr * 64 + mi * 16 + q * 4 + rr;
        int Cg = cj * 128 + wc * 64 + ni * 16 + lm;
        float e = (R != Cg) ? __expf(acc[mi][ni][rr] - EXP_OFF) : 0.f;
        rsum[mi][rr] += e;
        csum[ni] += e;
      }
    }
  }

  // Row-sums: reduce across the 16 lm lanes (q preserved).
#pragma unroll
  for (int mi = 0; mi < 4; mi++) {
#pragma unroll
    for (int rr = 0; rr < 4; rr++) {
      float s = rsum[mi][rr];
      s += __shfl_xor(s, 1);
      s += __shfl_xor(s, 2);
      s += __shfl_xor(s, 4);
      s += __shfl_xor(s, 8);
      if (lm == 0) {
        int R = ri * 128 + wr * 64 + mi * 16 + q * 4 + rr;
        part[((size_t)(b * 4096 + R)) * 64 + cj * 2 + wc] = s;
      }
    }
  }

  // Col-sums (off-diagonal tiles only): reduce across the 4 q lanes.
  if (ri != cj) {
#pragma unroll
    for (int ni = 0; ni < 4; ni++) {
      float s = csum[ni];
      s += __shfl_xor(s, 16);
      s += __shfl_xor(s, 32);
      if (q == 0) {
        int Cg = cj * 128 + wc * 64 + ni * 16 + lm;
        part[((size_t)(b * 4096 + Cg)) * 64 + ri * 2 + wr] = s;
      }
    }
  }
}

// lse_temp[row] = 80 + log(sum of 64 partials). One thread per row.
__global__ __launch_bounds__(256) void merge_row_kernel(
    const float* __restrict__ part, float* __restrict__ lse_temp) {
  int row = blockIdx.x * 256 + threadIdx.x;  // 0..16383
  const float4* p = (const float4*)(part + (size_t)row * 64);
  float s = 0.f;
#pragma unroll
  for (int i = 0; i < 16; i++) {
    float4 v = p[i];
    s += v.x + v.y + v.z + v.w;
  }
  lse_temp[row] = EXP_OFF + __logf(s);
}

// ---------------------------------------------------------------------------
// L4. Combine + top-7 (1 block; writes idx[7]).
// ---------------------------------------------------------------------------
__global__ __launch_bounds__(256) void combine_topk_kernel(
    const float* __restrict__ lse_inst, const float* __restrict__ lse_temp,
    const float* __restrict__ posdot, int* __restrict__ index_out) {
  __shared__ float wmax[4];
  __shared__ int widx[4];
  int tid = threadIdx.x;
  int base = tid * 8;
  float v[8];
#pragma unroll
  for (int r = 0; r < 8; r++) {
    int t = base + r;
    float sum = 0.f;
#pragma unroll
    for (int b = 0; b < 4; b++) {
      sum += 0.25f * (lse_inst[t * 8 + b] + lse_inst[t * 8 + 4 + b] +
                      lse_temp[b * 4096 + t] + lse_temp[b * 4096 + 2048 + t]) -
             posdot[b * 2048 + t];
    }
    v[r] = sum * 0.25f;
  }
  int lane = tid & 63, w = tid >> 6;
  for (int k = 0; k < 7; k++) {
    float bv = v[0];
    int bi = base;
#pragma unroll
    for (int r = 1; r < 8; r++)
      if (v[r] > bv) { bv = v[r]; bi = base + r; }
#pragma unroll
    for (int d = 1; d < 64; d <<= 1) {
      float ov = __shfl_xor(bv, d);
      int oi = __shfl_xor(bi, d);
      if (ov > bv || (ov == bv && oi < bi)) { bv = ov; bi = oi; }
    }
    if (lane == 0) { wmax[w] = bv; widx[w] = bi; }
    __syncthreads();
    float BV = wmax[0];
    int BI = widx[0];
#pragma unroll
    for (int ww = 1; ww < 4; ww++)
      if (wmax[ww] > BV || (wmax[ww] == BV && widx[ww] < BI)) {
        BV = wmax[ww];
        BI = widx[ww];
      }
    if (tid == 0) index_out[k] = BI;
    if (BI >= base && BI < base + 8) v[BI - base] = -INFINITY;
    __syncthreads();
  }
}

// ---------------------------------------------------------------------------
// L5. Fixup: rewrite the 7 special rows as running means. One block per bh
// (32 blocks); wave w handles k = {w, w+4}; lane e = element.
// run = psum prefix + V walk to l; out = run/(l+1).
// ---------------------------------------------------------------------------
__global__ __launch_bounds__(256) void fixup_kernel(
    const float* __restrict__ V, const float* __restrict__ psum,
    const int* __restrict__ index, float* __restrict__ out) {
  int bh = blockIdx.x;              // 0..31
  int h = bh & 7, b = bh >> 3;
  int tid = threadIdx.x;
  int e = tid & 63, w = tid >> 6;

  const float* ps = psum + (size_t)bh * 64 * 64;
  const float* Vbase = V + (size_t)(b * 2048) * 512 + h * 64 + e;
  float* obase = out + (size_t)bh * 2048 * 64 + e;

  for (int k = w; k < 7; k += 4) {
    int l = index[k];
    int g = l >> 5;
    float run = 0.f;
    for (int gg = 0; gg < g; ++gg) run += ps[gg * 64 + e];
    for (int ll = g * 32; ll <= l; ++ll) run += Vbase[(size_t)ll * 512];
    obase[(size_t)l * 64] = run / (float)(l + 1);
  }
}

extern "C" void kernel_launch(void* const* d_in, const int* in_sizes, int n_in,
                              void* d_out, int out_size, void* d_ws, size_t ws_size,
                              hipStream_t stream) {
  const float* Q = (const float*)d_in[0];  // (4,2048,512)
  const float* K = (const float*)d_in[1];
  const float* V = (const float*)d_in[2];
  float* out = (float*)d_out;              // (4,8,2048,64)

  // Workspace layout:
  unsigned short* Z = (unsigned short*)d_ws;        // 4*4096*512 bf16 = 16.8 MB
  float* base = (float*)d_ws + 4 * 4096 * 512 / 2;  // after Z
  float* part = base;                               // 1048576 floats
  float* lse_t = part + 1048576;                    // 16384
  float* lse_i = lse_t + 16384;                     // 16384
  float* posd = lse_i + 16384;                      // 8192
  float* psum = posd + 8192;                        // 131072 (512 KB)
  int* idx = (int*)(psum + 131072);                 // 8

  // L1: blocks 0..4095 convert; 4096..4607 psum (V only).
  convert_psum_kernel<<<4608, 256, 0, stream>>>(Q, K, Z, V, psum);
  // L2: 0..2111 gram; 2112..2367 instance; 2368..2879 bulk cumsum write.
  temporal_gemm_kernel<<<2880, 256, 0, stream>>>(Z, part, lse_i, posd, V,
                                                 psum, out);
  merge_row_kernel<<<64, 256, 0, stream>>>(part, lse_t);
  combine_topk_kernel<<<1, 256, 0, stream>>>(lse_i, lse_t, posd, idx);
  fixup_kernel<<<32, 256, 0, stream>>>(V, psum, idx, out);
}

// Round 11
// 182.938 us; speedup vs baseline: 1.1028x; 1.1028x over previous
//
#include <hip/hip_runtime.h>
#include <math.h>

// Problem constants: B=4, L=T=2048, H=8, E=64, C=H*E=512, top_k=7
// Output = cumsum(V) with top-7 rows (by corrmean) replaced by running mean.
// R6: symmetric gram -> upper-triangle tiles. R9: cumsum psum/write split.
// R10/R11/R16: deep-pipeline & depth-3 attempts REGRESSED (occupancy /
//     regime). R12: reg-clamp spills. R17: atomics +4.4us; launch count is
//     a dead lever. R18: bulk-write tail in temporal NOT overlapped
//     (uniform blocks -> synchronized rounds) -> +18us. REVERTED.
// CALIBRATION (R14/R16/R17/R18): total = temporal_dispatch + ~127 us.
//     The fixed part is insensitive to kernel placement -> only lever is
//     the temporal dispatch.
// R19 (this round): R14 (182.8 best) byte-identical EXCEPT grid rounds:
//     2368 blocks @ 768 resident = 4 synchronized rounds (uniform-duration
//     gram blocks); 4th round = 64 blocks on a ~idle GPU ~= +14 us.
//     Pack instance (1024 wave-units) into 192 blocks (768 slots, slots
//     <256 take a 2nd unit via +768 stride) -> grid 2304 = exactly 3
//     rounds. Predicted temporal 56.2 -> ~44-50 us.

typedef __attribute__((ext_vector_type(8))) short short8;
typedef __attribute__((ext_vector_type(8))) unsigned short ushort8;
typedef __attribute__((ext_vector_type(4))) float f32x4;

typedef const __attribute__((address_space(1))) void* gas_ptr;
typedef __attribute__((address_space(3))) void* las_ptr;

#define EXP_OFF 80.0f

__device__ __forceinline__ void async_cp16(const void* g, void* l) {
  // LDS dest is wave-uniform base; HW adds lane*16 (m104/m108).
  __builtin_amdgcn_global_load_lds((gas_ptr)g, (las_ptr)l, 16, 0, 0);
}

__device__ __forceinline__ unsigned short f2bf(float x) {
  union { float f; unsigned int u; } v; v.f = x;
  unsigned int r = v.u + 0x7FFFu + ((v.u >> 16) & 1u);  // RNE
  return (unsigned short)(r >> 16);
}

// ---------------------------------------------------------------------------
// Convert Q,K fp32 -> Z bf16 [4][4096][512] (rows 0..2047 = Q, 2048.. = K)
// ---------------------------------------------------------------------------
__global__ __launch_bounds__(256) void convert_bf16_kernel(
    const float* __restrict__ Q, const float* __restrict__ K,
    unsigned short* __restrict__ Z) {
  int tid = blockIdx.x * 256 + threadIdx.x;  // 0..1048575
  int row = tid >> 6;                        // b*4096 + i
  int c0 = (tid & 63) * 8;
  int b = row >> 12, i = row & 4095;
  const float* src = (i < 2048)
      ? Q + ((size_t)(b * 2048 + i) * 512 + c0)
      : K + ((size_t)(b * 2048 + (i - 2048)) * 512 + c0);
  float4 v0 = ((const float4*)src)[0];
  float4 v1 = ((const float4*)src)[1];
  ushort8 o;
  o[0] = f2bf(v0.x); o[1] = f2bf(v0.y); o[2] = f2bf(v0.z); o[3] = f2bf(v0.w);
  o[4] = f2bf(v1.x); o[5] = f2bf(v1.y); o[6] = f2bf(v1.z); o[7] = f2bf(v1.w);
  *(ushort8*)(Z + (size_t)row * 512 + c0) = o;
}

// ---------------------------------------------------------------------------
// Temporal gram (blocks 0..2111): upper-triangle 128x128 tiles (ri<=cj over
// 32x32 tile grid), 16x16x32 bf16 MFMA, BK=32, 3-slot LDS ring, counted
// vmcnt(4) + one raw s_barrier per kc (R14-verified).
// XOR-swizzled staging (bank-conflict 0 verified). XCD-pair swizzle:
// b=(id&7)>>1. Epilogue: e=exp(v-80) feeds row-sums (slot cj*2+wc) and,
// off-diagonal, col-sums (slot ri*2+wr) -- slot union [0,64) complete.
// Blocks 2112..2303: instance-LSE path, 768 wave-slots covering 1024
// wave-units via +768 stride (grid = 2304 = exactly 3 rounds at 3 blk/CU).
// __launch_bounds__(256,3): VGPR-76 regime, zero spills (R12 lesson).
// ---------------------------------------------------------------------------
__global__ __launch_bounds__(256, 3) void temporal_gemm_kernel(
    const unsigned short* __restrict__ Z, float* __restrict__ part,
    float* __restrict__ lse_inst /* [2048][8] */,
    float* __restrict__ posdot /* [4][2048] */) {
  __shared__ __align__(16) unsigned short As[3][128 * 32];  // 3 x 8 KB
  __shared__ __align__(16) unsigned short Bs[3][128 * 32];  // 3 x 8 KB

  if (blockIdx.x >= 2112) {
    // ---------------- instance path (768 slots, 1024 units) ---------------
    int slot = ((blockIdx.x - 2112) * 256 + threadIdx.x) >> 6;  // 0..767
    int lane = threadIdx.x & 63;
    int lm = lane & 15, q = lane >> 4;
    int v = lm & 7;
    for (int wu = slot; wu < 1024; wu += 768) {
      int t0 = wu * 2;
      int tt = (lm < 8) ? t0 : t0 + 1;
      size_t zrow = (v < 4) ? ((size_t)v * 4096 + tt)
                            : ((size_t)(v - 4) * 4096 + 2048 + tt);
      const unsigned short* g = Z + zrow * 512 + q * 8;

      f32x4 acc0 = (f32x4)(0.f), acc1 = (f32x4)(0.f);
#pragma unroll
      for (int kc = 0; kc < 16; kc += 2) {
        short8 a0 = *(const short8*)(g + kc * 32);
        short8 a1 = *(const short8*)(g + kc * 32 + 32);
        acc0 = __builtin_amdgcn_mfma_f32_16x16x32_bf16(a0, a0, acc0, 0, 0, 0);
        acc1 = __builtin_amdgcn_mfma_f32_16x16x32_bf16(a1, a1, acc1, 0, 0, 0);
      }
      f32x4 acc = acc0 + acc1;

#pragma unroll
      for (int rr = 0; rr < 4; rr++) {
        int i = q * 4 + rr;                      // row 0..15
        float val = acc[rr];
        bool samehalf = ((i < 8) == (lm < 8));
        int t = (i < 8) ? t0 : t0 + 1;
        int iv = i & 7;
        if (samehalf && iv < 4 && (lm & 7) == iv + 4)
          posdot[iv * 2048 + t] = val;
        float dd = (samehalf && lm != i) ? val : -INFINITY;
        float mt = dd;
        mt = fmaxf(mt, __shfl_xor(mt, 1));
        mt = fmaxf(mt, __shfl_xor(mt, 2));
        mt = fmaxf(mt, __shfl_xor(mt, 4));
        float e = __expf(dd - mt);
        e += __shfl_xor(e, 1);
        e += __shfl_xor(e, 2);
        e += __shfl_xor(e, 4);
        if ((lm & 7) == 0 && samehalf) lse_inst[t * 8 + iv] = mt + __logf(e);
      }
    }
    return;
  }

  // ------------------------- gram path (R14 verbatim) ---------------------
  int id = blockIdx.x;                  // 0..2111
  int x = id & 7;
  int b = x >> 1;                       // XCD-pair lock per batch
  int t = (id >> 3) * 2 + (x & 1);      // 0..527
  // invert t = cj*(cj+1)/2 + ri, ri<=cj
  int cj = (int)((sqrtf(8.0f * (float)t + 1.0f) - 1.0f) * 0.5f);
  while ((cj + 1) * (cj + 2) / 2 <= t) cj++;
  while (cj * (cj + 1) / 2 > t) cj--;
  int ri = t - cj * (cj + 1) / 2;
  const unsigned short* Zb = Z + (size_t)b * 4096 * 512;

  int tid = threadIdx.x;
  int w = tid >> 6, lane = tid & 63;
  int wr = w >> 1, wc = w & 1;
  int lm = lane & 15, q = lane >> 4;
  int swz = q ^ ((lm >> 1) & 3);  // frag-read physical chunk

  // Staging: slot row = w*16 + (lane>>2), physical chunk lane&3 holds
  // logical chunk kq = (lane&3)^((lane>>3)&3)
  int srow = lane >> 2;
  int kq = (lane & 3) ^ ((lane >> 3) & 3);
  int rl0 = w * 16 + srow;
  int rl1 = 64 + rl0;
  const unsigned short* gA0 = Zb + (size_t)(ri * 128 + rl0) * 512 + kq * 8;
  const unsigned short* gA1 = Zb + (size_t)(ri * 128 + rl1) * 512 + kq * 8;
  const unsigned short* gB0 = Zb + (size_t)(cj * 128 + rl0) * 512 + kq * 8;
  const unsigned short* gB1 = Zb + (size_t)(cj * 128 + rl1) * 512 + kq * 8;
  int lo0 = (w * 16) * 32;        // wave-uniform base offsets
  int lo1 = (64 + w * 16) * 32;

  f32x4 acc[4][4];
#pragma unroll
  for (int mi = 0; mi < 4; mi++)
#pragma unroll
    for (int ni = 0; ni < 4; ni++) acc[mi][ni] = (f32x4)(0.f);

#define STAGE(kc_, sl_)                                  \
  do {                                                   \
    int go_ = (kc_) * 32;                                \
    async_cp16(gA0 + go_, As[sl_] + lo0);                \
    async_cp16(gA1 + go_, As[sl_] + lo1);                \
    async_cp16(gB0 + go_, Bs[sl_] + lo0);                \
    async_cp16(gB1 + go_, Bs[sl_] + lo1);                \
  } while (0)

  // Prologue: tiles 0,1 into slots 0,1 (8 loads outstanding per wave).
  STAGE(0, 0);
  STAGE(1, 1);

  int sl = 0;  // ring slot holding tile kc
  for (int kc = 0; kc < 16; ++kc) {
    // Wait for tile kc's 4 loads (oldest); keep newer tiles in flight.
    if (kc < 15)
      asm volatile("s_waitcnt vmcnt(4)" ::: "memory");
    else
      asm volatile("s_waitcnt vmcnt(0)" ::: "memory");
    // One barrier per kc: all waves have tile kc landed AND consumed their
    // tile-(kc-1) ds_reads (frag regs force lgkmcnt before MFMA issue).
    asm volatile("s_barrier" ::: "memory");

    // Stage tile kc+2 into the slot read at kc-1 (now provably free).
    if (kc + 2 < 16) {
      int ss = sl + 2;
      if (ss >= 3) ss -= 3;
      STAGE(kc + 2, ss);
    }

    short8 af[4], bfr[4];
#pragma unroll
    for (int mi = 0; mi < 4; mi++) {
      int ar = wr * 64 + mi * 16 + lm;
      af[mi] = *(const short8*)(As[sl] + ar * 32 + swz * 8);
    }
#pragma unroll
    for (int ni = 0; ni < 4; ni++) {
      int bc = wc * 64 + ni * 16 + lm;
      bfr[ni] = *(const short8*)(Bs[sl] + bc * 32 + swz * 8);
    }
#pragma unroll
    for (int mi = 0; mi < 4; mi++)
#pragma unroll
      for (int ni = 0; ni < 4; ni++)
        acc[mi][ni] = __builtin_amdgcn_mfma_f32_16x16x32_bf16(
            af[mi], bfr[ni], acc[mi][ni], 0, 0, 0);

    sl = (sl + 1 == 3) ? 0 : sl + 1;
  }
#undef STAGE

  // Epilogue. C/D layout: col=lane&15, row=(lane>>4)*4+reg (m89-verified).
  float rsum[4][4];  // per (mi, rr): sum over ni, lm-reduced later
  float csum[4];     // per ni: sum over mi, rr, q-reduced later
#pragma unroll
  for (int mi = 0; mi < 4; mi++)
#pragma unroll
    for (int rr = 0; rr < 4; rr++) rsum[mi][rr] = 0.f;
#pragma unroll
  for (int ni = 0; ni < 4; ni++) csum[ni] = 0.f;

#pragma unroll
  for (int mi = 0; mi < 4; mi++) {
#pragma unroll
    for (int ni = 0; ni < 4; ni++) {
#pragma unroll
      for (int rr = 0; rr < 4; rr++) {
        int R = ri * 128 + wr * 64 + mi * 16 + q * 4 + rr;
        int Cg = cj * 128 + wc * 64 + ni * 16 + lm;
        float e = (R != Cg) ? __expf(acc[mi][ni][rr] - EXP_OFF) : 0.f;
        rsum[mi][rr] += e;
        csum[ni] += e;
      }
    }
  }

  // Row-sums: reduce across the 16 lm lanes (q preserved).
#pragma unroll
  for (int mi = 0; mi < 4; mi++) {
#pragma unroll
    for (int rr = 0; rr < 4; rr++) {
      float s = rsum[mi][rr];
      s += __shfl_xor(s, 1);
      s += __shfl_xor(s, 2);
      s += __shfl_xor(s, 4);
      s += __shfl_xor(s, 8);
      if (lm == 0) {
        int R = ri * 128 + wr * 64 + mi * 16 + q * 4 + rr;
        part[((size_t)(b * 4096 + R)) * 64 + cj * 2 + wc] = s;
      }
    }
  }

  // Col-sums (off-diagonal tiles only): reduce across the 4 q lanes.
  if (ri != cj) {
#pragma unroll
    for (int ni = 0; ni < 4; ni++) {
      float s = csum[ni];
      s += __shfl_xor(s, 16);
      s += __shfl_xor(s, 32);
      if (q == 0) {
        int Cg = cj * 128 + wc * 64 + ni * 16 + lm;
        part[((size_t)(b * 4096 + Cg)) * 64 + ri * 2 + wr] = s;
      }
    }
  }
}

// lse_temp[row] = 80 + log(sum of 64 partials). One thread per row.
__global__ __launch_bounds__(256) void merge_row_kernel(
    const float* __restrict__ part, float* __restrict__ lse_temp) {
  int row = blockIdx.x * 256 + threadIdx.x;  // 0..16383
  const float4* p = (const float4*)(part + (size_t)row * 64);
  float s = 0.f;
#pragma unroll
  for (int i = 0; i < 16; i++) {
    float4 v = p[i];
    s += v.x + v.y + v.z + v.w;
  }
  lse_temp[row] = EXP_OFF + __logf(s);
}

// ---------------------------------------------------------------------------
// Fused combine+topk (block 0) and cumsum phase A (blocks 1..512).
// ---------------------------------------------------------------------------
__global__ __launch_bounds__(256) void combine_psum_kernel(
    const float* __restrict__ lse_inst, const float* __restrict__ lse_temp,
    const float* __restrict__ posdot, int* __restrict__ index_out,
    const float* __restrict__ V, float* __restrict__ psum) {
  if (blockIdx.x > 0) {
    // ---------------- cumsum phase A -------------------------------------
    int gb = (blockIdx.x - 1) * 4 + (threadIdx.x >> 6);  // 0..2047
    int bh = gb >> 6, g = gb & 63;
    int h = bh & 7, b = bh >> 3;
    int lane = threadIdx.x & 63;
    int ro = lane >> 4, e4 = (lane & 15) * 4;
    const float* base =
        V + (size_t)(b * 2048 + g * 32 + ro) * 512 + h * 64 + e4;
    float sx = 0.f, sy = 0.f, sz = 0.f, sw = 0.f;
#pragma unroll
    for (int k = 0; k < 8; k++) {
      float4 v = *(const float4*)(base + (size_t)(k * 4) * 512);
      sx += v.x; sy += v.y; sz += v.z; sw += v.w;
    }
    sx += __shfl_xor(sx, 16); sy += __shfl_xor(sy, 16);
    sz += __shfl_xor(sz, 16); sw += __shfl_xor(sw, 16);
    sx += __shfl_xor(sx, 32); sy += __shfl_xor(sy, 32);
    sz += __shfl_xor(sz, 32); sw += __shfl_xor(sw, 32);
    if (ro == 0) {
      float4 o = {sx, sy, sz, sw};
      *(float4*)(psum + ((size_t)bh * 64 + g) * 64 + e4) = o;
    }
    return;
  }

  // ---------------- combine + top-7 ---------------------------------------
  __shared__ float wmax[4];
  __shared__ int widx[4];
  int tid = threadIdx.x;
  int base = tid * 8;
  float v[8];
#pragma unroll
  for (int r = 0; r < 8; r++) {
    int t = base + r;
    float sum = 0.f;
#pragma unroll
    for (int b = 0; b < 4; b++) {
      sum += 0.25f * (lse_inst[t * 8 + b] + lse_inst[t * 8 + 4 + b] +
                      lse_temp[b * 4096 + t] + lse_temp[b * 4096 + 2048 + t]) -
             posdot[b * 2048 + t];
    }
    v[r] = sum * 0.25f;
  }
  int lane = tid & 63, w = tid >> 6;
  for (int k = 0; k < 7; k++) {
    float bv = v[0];
    int bi = base;
#pragma unroll
    for (int r = 1; r < 8; r++)
      if (v[r] > bv) { bv = v[r]; bi = base + r; }
#pragma unroll
    for (int d = 1; d < 64; d <<= 1) {
      float ov = __shfl_xor(bv, d);
      int oi = __shfl_xor(bi, d);
      if (ov > bv || (ov == bv && oi < bi)) { bv = ov; bi = oi; }
    }
    if (lane == 0) { wmax[w] = bv; widx[w] = bi; }
    __syncthreads();
    float BV = wmax[0];
    int BI = widx[0];
#pragma unroll
    for (int ww = 1; ww < 4; ww++)
      if (wmax[ww] > BV || (wmax[ww] == BV && widx[ww] < BI)) {
        BV = wmax[ww];
        BI = widx[ww];
      }
    if (tid == 0) index_out[k] = BI;
    if (BI >= base && BI < base + 8) v[BI - base] = -INFINITY;
    __syncthreads();
  }
}

// ---------------------------------------------------------------------------
// Cumsum phase B: scan + write. grid = 32 bh * 16 chunks = 512 blocks.
// ---------------------------------------------------------------------------
__global__ __launch_bounds__(256) void cumsum_write_kernel(
    const float* __restrict__ V, const float* __restrict__ psum,
    const int* __restrict__ index, float* __restrict__ out) {
  int blk = blockIdx.x;             // 0..511
  int bh = blk >> 4, chunk = blk & 15;
  int h = bh & 7, b = bh >> 3;
  int tid = threadIdx.x;
  int e = tid & 63, sub = tid >> 6;
  int g = chunk * 4 + sub;          // 0..63

  const float* ps = psum + (size_t)bh * 64 * 64;
  float run = 0.f;
  for (int gg = 0; gg < g; ++gg) run += ps[gg * 64 + e];

  int idx[7];
#pragma unroll
  for (int k = 0; k < 7; k++) idx[k] = index[k];

  const float* Vbase = V + (size_t)(b * 2048) * 512 + h * 64 + e;
  float* obase = out + (size_t)bh * 2048 * 64 + e;

  int l0 = g * 32;
#pragma unroll 4
  for (int l = l0; l < l0 + 32; ++l) {
    run += Vbase[(size_t)l * 512];
    float o = run;
    bool special = false;
#pragma unroll
    for (int k = 0; k < 7; k++) special = special || (idx[k] == l);
    if (special) o = run / (float)(l + 1);
    obase[(size_t)l * 64] = o;
  }
}

extern "C" void kernel_launch(void* const* d_in, const int* in_sizes, int n_in,
                              void* d_out, int out_size, void* d_ws, size_t ws_size,
                              hipStream_t stream) {
  const float* Q = (const float*)d_in[0];  // (4,2048,512)
  const float* K = (const float*)d_in[1];
  const float* V = (const float*)d_in[2];
  float* out = (float*)d_out;              // (4,8,2048,64)

  // Workspace layout:
  unsigned short* Z = (unsigned short*)d_ws;        // 4*4096*512 bf16 = 16.8 MB
  float* base = (float*)d_ws + 4 * 4096 * 512 / 2;  // after Z
  float* part = base;                               // 4*4096*64 = 1M floats
  float* lse_t = base + 4 * 4096 * 64;              // 16384
  float* lse_i = lse_t + 16384;                     // 16384
  float* posd = lse_i + 16384;                      // 8192
  int* idx = (int*)(posd + 8192);                   // 8
  float* psum = part;  // 32*64*64 floats = 512 KB, reuses dead `part`

  convert_bf16_kernel<<<4096, 256, 0, stream>>>(Q, K, Z);
  // Blocks 0..2111: gram tiles; 2112..2303: instance path (768 slots for
  // 1024 wave-units). Grid 2304 = exactly 3 rounds at 3 blocks/CU.
  temporal_gemm_kernel<<<2304, 256, 0, stream>>>(Z, part, lse_i, posd);
  merge_row_kernel<<<64, 256, 0, stream>>>(part, lse_t);
  // Block 0: combine+top7; blocks 1..512: cumsum psum (part dead after
  // merge_row; safe to overlay).
  combine_psum_kernel<<<513, 256, 0, stream>>>(lse_i, lse_t, posd, idx, V,
                                               psum);
  cumsum_write_kernel<<<512, 256, 0, stream>>>(V, psum, idx, out);
}